// Round 7
// baseline (176.991 us; speedup 1.0000x reference)
//
#include <hip/hip_runtime.h>
#include <math.h>

typedef _Float16 h2_t __attribute__((ext_vector_type(2)));
typedef _Float16 h4_t __attribute__((ext_vector_type(4)));
typedef _Float16 h8_t __attribute__((ext_vector_type(8)));

#define NP 32
#define KC 31
#define HH 512
#define WW 512
#define BB 4
#define CC 3

#define TXO 64        // 64-wide tile
#define TYO 16        // 16 output rows -> 256-thread block, 4x more blocks
#define NT 256        // threads per block
#define TROWS 46      // 16 outputs + 15 + 15 halo
#define TWORDS 48     // row stride in h2 words (KEEP: 4ty x 16tx quarter-wave
                      // covers all 32 banks exactly once -> conflict-free b64)
#define TILEW (TROWS * TWORDS)   // 2208 h2 words per channel tile
#define WSTR 36       // weight table plane stride in h2 words

// HARD CONSTRAINTS (measured R0-R6):
//  - grid z = BB; >128 VGPRs unobtainable -> 4 outputs/thread (wj[64]);
//    insert-style unpack; fdot2/pk_fma half-rate -> R6 fold (dy 31->16) kept.
//  - NOTHING register-live across the wj-resident compute loop (R1/R2/R3
//    spilled 15/52/92 MB WRITE). global_load_lds loses L2 halo reuse.
//  - Barriers NOT the bottleneck (R5). VALU NOT the bottleneck (R6: fdot2
//    count halved, VALU busy 51->34us, duration UNCHANGED at 85us).
//  - Neither pipe >41% busy -> latency-bound, under-occupied. Occupancy
//    counter has read ~19% (~6 waves/CU vs 16 expected) in EVERY round.
// THIS ROUND (single variable): 256-thread blocks x 1024 (TYO 32->16) to
// test residency. Per-thread work, wj, dy-loop, bank geometry identical.
// wtab build: 4 passes x 8 planes (same 32-lane groups, bit-identical).

__device__ __forceinline__ double plane_of(int i) {
    const double stepd = 50.0 / 31.0;
    return (i < 31) ? (double)i * stepd : 50.0;
}

__launch_bounds__(256, 4)
__global__ void defocus_kernel(const float* __restrict__ img,
                               const float* __restrict__ coc,
                               float* __restrict__ out) {
    const int tx = threadIdx.x;            // 0..15
    const int ty = threadIdx.y;            // 0..15
    const int tid = ty * 16 + tx;
    const int tilex = blockIdx.x * TXO;
    const int tiley = blockIdx.y * TYO;
    const int b = blockIdx.z;

    __shared__ __align__(16) h2_t wtab[NP * WSTR];   //  4608 B
    __shared__ __align__(16) h2_t tile[3 * TILEW];   // 26496 B (total 31104)

    const int yo = tiley + ty;
    const int xo = tilex + tx * 4;

    // ---- (1) coc load first; its latency hides under the wtab build
    const float4 cv = *(const float4*)&coc[((size_t)b * HH + yo) * WW + xo];

    // ---- (2) in-block wtab build (bit-identical values; 4 passes x 8 planes
    //          for the 256-thread block). f64/expf temps die before staging.
    {
        const int t = tid & 31;               // padded tap position 0..31
        #pragma unroll
        for (int pass = 0; pass < 4; ++pass) {
            const int p = (tid >> 5) + 8 * pass;    // plane 0..31
            const double stepd = 50.0 / 31.0;
            double cocp = (p < 31) ? (double)p * stepd : 50.0;  // numpy linspace
            float gt;
            if (cocp < 0.5) {
                gt = (t == 15) ? 1.f : 0.f;   // identity plane (plane 0 only)
            } else {
                double sigma = cocp / 2.355;
                int k = (int)(2.0 * cocp + 1.0);   // trunc, matches python int()
                if ((k & 1) == 0) k += 1;
                if (k > KC) k = KC;
                int h = k / 2;
                int d = t - 15;
                float denom = (float)(2.0 * sigma * sigma);
                float v = (d >= -h && d <= h && t < KC) ? expf(-(float)(d * d) / denom) : 0.f;
                float s = v;
                #pragma unroll
                for (int off = 1; off < 32; off <<= 1) s += __shfl_xor(s, off, 32);
                gt = v / s;
            }
            const int m = t & 15;
            const int s0 = (t < 16) ? (2 * m) : ((2 * m - 1 < 0) ? 0 : 2 * m - 1);
            const int s1 = (t < 16) ? (2 * m + 1) : (2 * m);
            float w0 = __shfl(gt, s0, 32);
            float w1 = __shfl(gt, s1, 32);
            if (t >= 16 && (2 * m - 1) < 0) w0 = 0.f;   // g[-1] = 0
            h2_t w; w.x = (_Float16)w0; w.y = (_Float16)w1;
            wtab[p * WSTR + t] = w;
            if (t < WSTR - 32) {
                h2_t z; z.x = (_Float16)0.f; z.y = (_Float16)0.f;
                wtab[p * WSTR + 32 + t] = z;
            }
        }
    }

    // ---- (3) per-pixel bin index, exact double-precision boundary semantics
    const float cocf[4] = {cv.x, cv.y, cv.z, cv.w};
    int idx[4];
    #pragma unroll
    for (int j = 0; j < 4; ++j) {
        const double stepd = 50.0 / 31.0;
        double cd = (double)cocf[j];
        int i0 = (int)floor(cd / stepd + 0.5);
        i0 = min(max(i0, 0), 31);
        if (i0 > 0 && cd <= 0.5 * (plane_of(i0 - 1) + plane_of(i0))) {
            i0 -= 1;
        } else if (i0 < 31 && cd > 0.5 * (plane_of(i0) + plane_of(i0 + 1))) {
            i0 += 1;
        }
        idx[j] = i0;
    }

    // Fence: forbid hoisting staging loads up across the f64 region (R1 spill).
    __builtin_amdgcn_sched_barrier(0);

    // ---- (4) stage ALL THREE channels into private tiles, back-to-back.
    #pragma unroll 1
    for (int c = 0; c < CC; ++c) {
        const float* src = img + (size_t)(b * CC + c) * HH * WW;
        h2_t* tdst = tile + c * TILEW;
        for (int f = tid; f < TILEW; f += NT) {
            int r = f / TWORDS;
            int w = f - r * TWORDS;
            int gy = tiley - 15 + r;
            int gx = tilex - 15 + 2 * w;
            float v0 = 0.f, v1 = 0.f;
            if ((unsigned)gy < (unsigned)HH) {
                if ((unsigned)gx < (unsigned)WW) v0 = src[gy * WW + gx];
                if ((unsigned)(gx + 1) < (unsigned)WW) v1 = src[gy * WW + gx + 1];
            }
            h2_t pv; pv.x = (_Float16)v0; pv.y = (_Float16)v1;
            tdst[f] = pv;
        }
    }

    __syncthreads();   // the ONLY barrier: wtab + all three tiles staged

    // ---- (5) gather this thread's 4 weight rows into registers
    // even local col (j=0,2): phase A; odd (j=1,3): phase B (pre-shifted one tap)
    h2_t wj[4][16];
    #pragma unroll
    for (int j = 0; j < 4; ++j) {
        const h2_t* wp = &wtab[idx[j] * WSTR + (j & 1) * 16];
        #pragma unroll
        for (int m = 0; m < 4; ++m) {
            h8_t v = *(const h8_t*)(wp + 4 * m);   // 16B aligned: WSTR%4==0
            #pragma unroll
            for (int q = 0; q < 4; ++q) {
                h2_t t2; t2.x = v[2 * q]; t2.y = v[2 * q + 1];
                wj[j][4 * m + q] = t2;
            }
        }
    }

// horizontal dot over 17 live words (rs0/1 use rw[0..15], rs2/3 use rw[1..16])
#define HDOT(RW, RS0, RS1, RS2, RS3)                                         \
    {                                                                        \
        _Pragma("unroll")                                                    \
        for (int m = 0; m < 16; ++m) {                                       \
            RS0 = __builtin_amdgcn_fdot2(wj[0][m], RW[m],     RS0, false);   \
            RS1 = __builtin_amdgcn_fdot2(wj[1][m], RW[m],     RS1, false);   \
            RS2 = __builtin_amdgcn_fdot2(wj[2][m], RW[m + 1], RS2, false);   \
            RS3 = __builtin_amdgcn_fdot2(wj[3][m], RW[m + 1], RS3, false);   \
        }                                                                    \
    }

// column-weight extraction for compile-time DY (verified phase mapping)
#define CWEXT(DY, CW0, CW1, CW2, CW3)                                        \
    {                                                                        \
        if (((DY) & 1) == 0) {                                               \
            CW0 = (float)wj[0][(DY) >> 1].x;                                 \
            CW2 = (float)wj[2][(DY) >> 1].x;                                 \
            CW1 = (float)wj[1][(DY) >> 1].y;                                 \
            CW3 = (float)wj[3][(DY) >> 1].y;                                 \
        } else {                                                             \
            CW0 = (float)wj[0][(DY) >> 1].y;                                 \
            CW2 = (float)wj[2][(DY) >> 1].y;                                 \
            CW1 = (float)wj[1][((DY) + 1) >> 1].x;                           \
            CW3 = (float)wj[3][((DY) + 1) >> 1].x;                           \
        }                                                                    \
    }

    // ---- (6) three compute passes; symmetric fold: 16 hdots instead of 31
    #pragma unroll 1
    for (int c = 0; c < CC; ++c) {
        float acc0 = 0.f, acc1 = 0.f, acc2 = 0.f, acc3 = 0.f;
        const h2_t* rowbase = &tile[c * TILEW + ty * TWORDS + 2 * tx];

        // center row (dy = 15), unfolded
        {
            const h2_t* rp = rowbase + 15 * TWORDS;
            h2_t rw[18];
            #pragma unroll
            for (int m = 0; m < 9; ++m) {
                h4_t q = *(const h4_t*)(rp + 2 * m);   // ds_read_b64
                h2_t lo; lo.x = q[0]; lo.y = q[1];
                h2_t hi; hi.x = q[2]; hi.y = q[3];
                rw[2 * m]     = lo;
                rw[2 * m + 1] = hi;
            }
            float rs0 = 0.f, rs1 = 0.f, rs2 = 0.f, rs3 = 0.f;
            HDOT(rw, rs0, rs1, rs2, rs3)
            float cw0, cw1, cw2, cw3;
            CWEXT(15, cw0, cw1, cw2, cw3)
            acc0 += cw0 * rs0;  acc1 += cw1 * rs1;
            acc2 += cw2 * rs2;  acc3 += cw3 * rs3;
        }

        // folded pairs: rows 15-d and 15+d share weight g[15-d] (exact symmetry)
        #pragma unroll
        for (int d = 1; d <= 15; ++d) {
            const h2_t* rpa = rowbase + (15 - d) * TWORDS;
            const h2_t* rpb = rowbase + (15 + d) * TWORDS;
            h2_t rw[18];
            #pragma unroll
            for (int m = 0; m < 9; ++m) {
                h4_t qa = *(const h4_t*)(rpa + 2 * m);   // ds_read_b64
                h4_t qb = *(const h4_t*)(rpb + 2 * m);   // ds_read_b64
                h4_t qs = qa + qb;                       // 2x v_pk_add_f16
                h2_t lo; lo.x = qs[0]; lo.y = qs[1];
                h2_t hi; hi.x = qs[2]; hi.y = qs[3];
                rw[2 * m]     = lo;
                rw[2 * m + 1] = hi;
            }
            float rs0 = 0.f, rs1 = 0.f, rs2 = 0.f, rs3 = 0.f;
            HDOT(rw, rs0, rs1, rs2, rs3)
            const int dy = 15 - d;                       // compile-time (unrolled)
            float cw0, cw1, cw2, cw3;
            CWEXT(dy, cw0, cw1, cw2, cw3)
            acc0 += cw0 * rs0;  acc1 += cw1 * rs1;
            acc2 += cw2 * rs2;  acc3 += cw3 * rs3;
        }

        *(float4*)&out[((size_t)(b * CC + c) * HH + yo) * WW + xo] =
            make_float4(acc0, acc1, acc2, acc3);
    }

#undef HDOT
#undef CWEXT
}

extern "C" void kernel_launch(void* const* d_in, const int* in_sizes, int n_in,
                              void* d_out, int out_size, void* d_ws, size_t ws_size,
                              hipStream_t stream) {
    const float* sharp = (const float*)d_in[0];
    const float* cocm  = (const float*)d_in[1];
    float* out = (float*)d_out;

    dim3 grid(WW / TXO, HH / TYO, BB);   // 8 x 32 x 4 = 1024 blocks
    dim3 block(16, 16, 1);
    defocus_kernel<<<grid, block, 0, stream>>>(sharp, cocm, out);
}

// Round 8
// 131.246 us; speedup vs baseline: 1.3485x; 1.3485x over previous
//
#include <hip/hip_runtime.h>
#include <math.h>

typedef _Float16 h2_t __attribute__((ext_vector_type(2)));
typedef _Float16 h4_t __attribute__((ext_vector_type(4)));
typedef _Float16 h8_t __attribute__((ext_vector_type(8)));

#define NP 32
#define KC 31
#define HH 512
#define WW 512
#define BB 4
#define CC 3

#define TXO 64        // 64-wide tile
#define TYO 16        // 16 output rows -> 256-thread block
#define NT 256        // threads per block
#define TROWS 46      // 16 outputs + 15 + 15 halo
#define TWORDS 48     // row stride in h2 words (4ty x 16tx quarter-wave covers
                      // all 32 banks exactly once -> conflict-free b64)
#define TILEW (TROWS * TWORDS)   // 2208 h2 words per channel tile
#define WSTR 36       // weight table plane stride in h2 words

// HARD CONSTRAINTS (measured R0-R7):
//  - grid z = BB; wj[64] needs ~100 VGPRs -> VGPR cap must be >=128.
//    R7: __launch_bounds__(256,4) capped at 64 -> 158MB spill. THE CAP IS
//    THE SECOND ARG'S DOING; use (256,2) -> cap 256, allocator lands ~100.
//  - NOTHING register-live across the wj-resident compute loop (R1/R2/R3).
//  - Barriers NOT the bottleneck (R5). VALU NOT the bottleneck (R6: fdot2
//    halved -> busy 51->34us, duration unchanged).
//  - KEY FINDING (R0-R7): 512-thread blocks never co-reside -- occupancy
//    pinned ~20% (1 block/CU, 2 grid blocks/CU run SERIALLY, 85 = 2x42us).
//    256-thread blocks: occupancy 43% even while spill-crippled (R7).
// THIS ROUND: R7 geometry (256-thread blocks x 1024) with the correct
// VGPR cap. Expect 4 blocks/CU resident, latency finally hidden.

__device__ __forceinline__ double plane_of(int i) {
    const double stepd = 50.0 / 31.0;
    return (i < 31) ? (double)i * stepd : 50.0;
}

__launch_bounds__(256, 2)
__global__ void defocus_kernel(const float* __restrict__ img,
                               const float* __restrict__ coc,
                               float* __restrict__ out) {
    const int tx = threadIdx.x;            // 0..15
    const int ty = threadIdx.y;            // 0..15
    const int tid = ty * 16 + tx;
    const int tilex = blockIdx.x * TXO;
    const int tiley = blockIdx.y * TYO;
    const int b = blockIdx.z;

    __shared__ __align__(16) h2_t wtab[NP * WSTR];   //  4608 B
    __shared__ __align__(16) h2_t tile[3 * TILEW];   // 26496 B (total 31104)

    const int yo = tiley + ty;
    const int xo = tilex + tx * 4;

    // ---- (1) coc load first; its latency hides under the wtab build
    const float4 cv = *(const float4*)&coc[((size_t)b * HH + yo) * WW + xo];

    // ---- (2) in-block wtab build (bit-identical values; 4 passes x 8 planes,
    //          proven in R7). f64/expf temps die before staging.
    {
        const int t = tid & 31;               // padded tap position 0..31
        #pragma unroll
        for (int pass = 0; pass < 4; ++pass) {
            const int p = (tid >> 5) + 8 * pass;    // plane 0..31
            const double stepd = 50.0 / 31.0;
            double cocp = (p < 31) ? (double)p * stepd : 50.0;  // numpy linspace
            float gt;
            if (cocp < 0.5) {
                gt = (t == 15) ? 1.f : 0.f;   // identity plane (plane 0 only)
            } else {
                double sigma = cocp / 2.355;
                int k = (int)(2.0 * cocp + 1.0);   // trunc, matches python int()
                if ((k & 1) == 0) k += 1;
                if (k > KC) k = KC;
                int h = k / 2;
                int d = t - 15;
                float denom = (float)(2.0 * sigma * sigma);
                float v = (d >= -h && d <= h && t < KC) ? expf(-(float)(d * d) / denom) : 0.f;
                float s = v;
                #pragma unroll
                for (int off = 1; off < 32; off <<= 1) s += __shfl_xor(s, off, 32);
                gt = v / s;
            }
            const int m = t & 15;
            const int s0 = (t < 16) ? (2 * m) : ((2 * m - 1 < 0) ? 0 : 2 * m - 1);
            const int s1 = (t < 16) ? (2 * m + 1) : (2 * m);
            float w0 = __shfl(gt, s0, 32);
            float w1 = __shfl(gt, s1, 32);
            if (t >= 16 && (2 * m - 1) < 0) w0 = 0.f;   // g[-1] = 0
            h2_t w; w.x = (_Float16)w0; w.y = (_Float16)w1;
            wtab[p * WSTR + t] = w;
            if (t < WSTR - 32) {
                h2_t z; z.x = (_Float16)0.f; z.y = (_Float16)0.f;
                wtab[p * WSTR + 32 + t] = z;
            }
        }
    }

    // ---- (3) per-pixel bin index, exact double-precision boundary semantics
    const float cocf[4] = {cv.x, cv.y, cv.z, cv.w};
    int idx[4];
    #pragma unroll
    for (int j = 0; j < 4; ++j) {
        const double stepd = 50.0 / 31.0;
        double cd = (double)cocf[j];
        int i0 = (int)floor(cd / stepd + 0.5);
        i0 = min(max(i0, 0), 31);
        if (i0 > 0 && cd <= 0.5 * (plane_of(i0 - 1) + plane_of(i0))) {
            i0 -= 1;
        } else if (i0 < 31 && cd > 0.5 * (plane_of(i0) + plane_of(i0 + 1))) {
            i0 += 1;
        }
        idx[j] = i0;
    }

    // Fence: forbid hoisting staging loads up across the f64 region (R1 spill).
    __builtin_amdgcn_sched_barrier(0);

    // ---- (4) stage ALL THREE channels into private tiles, back-to-back.
    #pragma unroll 1
    for (int c = 0; c < CC; ++c) {
        const float* src = img + (size_t)(b * CC + c) * HH * WW;
        h2_t* tdst = tile + c * TILEW;
        for (int f = tid; f < TILEW; f += NT) {
            int r = f / TWORDS;
            int w = f - r * TWORDS;
            int gy = tiley - 15 + r;
            int gx = tilex - 15 + 2 * w;
            float v0 = 0.f, v1 = 0.f;
            if ((unsigned)gy < (unsigned)HH) {
                if ((unsigned)gx < (unsigned)WW) v0 = src[gy * WW + gx];
                if ((unsigned)(gx + 1) < (unsigned)WW) v1 = src[gy * WW + gx + 1];
            }
            h2_t pv; pv.x = (_Float16)v0; pv.y = (_Float16)v1;
            tdst[f] = pv;
        }
    }

    __syncthreads();   // the ONLY barrier: wtab + all three tiles staged

    // ---- (5) gather this thread's 4 weight rows into registers
    // even local col (j=0,2): phase A; odd (j=1,3): phase B (pre-shifted one tap)
    h2_t wj[4][16];
    #pragma unroll
    for (int j = 0; j < 4; ++j) {
        const h2_t* wp = &wtab[idx[j] * WSTR + (j & 1) * 16];
        #pragma unroll
        for (int m = 0; m < 4; ++m) {
            h8_t v = *(const h8_t*)(wp + 4 * m);   // 16B aligned: WSTR%4==0
            #pragma unroll
            for (int q = 0; q < 4; ++q) {
                h2_t t2; t2.x = v[2 * q]; t2.y = v[2 * q + 1];
                wj[j][4 * m + q] = t2;
            }
        }
    }

// horizontal dot over 17 live words (rs0/1 use rw[0..15], rs2/3 use rw[1..16])
#define HDOT(RW, RS0, RS1, RS2, RS3)                                         \
    {                                                                        \
        _Pragma("unroll")                                                    \
        for (int m = 0; m < 16; ++m) {                                       \
            RS0 = __builtin_amdgcn_fdot2(wj[0][m], RW[m],     RS0, false);   \
            RS1 = __builtin_amdgcn_fdot2(wj[1][m], RW[m],     RS1, false);   \
            RS2 = __builtin_amdgcn_fdot2(wj[2][m], RW[m + 1], RS2, false);   \
            RS3 = __builtin_amdgcn_fdot2(wj[3][m], RW[m + 1], RS3, false);   \
        }                                                                    \
    }

// column-weight extraction for compile-time DY (verified phase mapping)
#define CWEXT(DY, CW0, CW1, CW2, CW3)                                        \
    {                                                                        \
        if (((DY) & 1) == 0) {                                               \
            CW0 = (float)wj[0][(DY) >> 1].x;                                 \
            CW2 = (float)wj[2][(DY) >> 1].x;                                 \
            CW1 = (float)wj[1][(DY) >> 1].y;                                 \
            CW3 = (float)wj[3][(DY) >> 1].y;                                 \
        } else {                                                             \
            CW0 = (float)wj[0][(DY) >> 1].y;                                 \
            CW2 = (float)wj[2][(DY) >> 1].y;                                 \
            CW1 = (float)wj[1][((DY) + 1) >> 1].x;                           \
            CW3 = (float)wj[3][((DY) + 1) >> 1].x;                           \
        }                                                                    \
    }

    // ---- (6) three compute passes; symmetric fold: 16 hdots instead of 31
    #pragma unroll 1
    for (int c = 0; c < CC; ++c) {
        float acc0 = 0.f, acc1 = 0.f, acc2 = 0.f, acc3 = 0.f;
        const h2_t* rowbase = &tile[c * TILEW + ty * TWORDS + 2 * tx];

        // center row (dy = 15), unfolded
        {
            const h2_t* rp = rowbase + 15 * TWORDS;
            h2_t rw[18];
            #pragma unroll
            for (int m = 0; m < 9; ++m) {
                h4_t q = *(const h4_t*)(rp + 2 * m);   // ds_read_b64
                h2_t lo; lo.x = q[0]; lo.y = q[1];
                h2_t hi; hi.x = q[2]; hi.y = q[3];
                rw[2 * m]     = lo;
                rw[2 * m + 1] = hi;
            }
            float rs0 = 0.f, rs1 = 0.f, rs2 = 0.f, rs3 = 0.f;
            HDOT(rw, rs0, rs1, rs2, rs3)
            float cw0, cw1, cw2, cw3;
            CWEXT(15, cw0, cw1, cw2, cw3)
            acc0 += cw0 * rs0;  acc1 += cw1 * rs1;
            acc2 += cw2 * rs2;  acc3 += cw3 * rs3;
        }

        // folded pairs: rows 15-d and 15+d share weight g[15-d] (exact symmetry)
        #pragma unroll
        for (int d = 1; d <= 15; ++d) {
            const h2_t* rpa = rowbase + (15 - d) * TWORDS;
            const h2_t* rpb = rowbase + (15 + d) * TWORDS;
            h2_t rw[18];
            #pragma unroll
            for (int m = 0; m < 9; ++m) {
                h4_t qa = *(const h4_t*)(rpa + 2 * m);   // ds_read_b64
                h4_t qb = *(const h4_t*)(rpb + 2 * m);   // ds_read_b64
                h4_t qs = qa + qb;                       // 2x v_pk_add_f16
                h2_t lo; lo.x = qs[0]; lo.y = qs[1];
                h2_t hi; hi.x = qs[2]; hi.y = qs[3];
                rw[2 * m]     = lo;
                rw[2 * m + 1] = hi;
            }
            float rs0 = 0.f, rs1 = 0.f, rs2 = 0.f, rs3 = 0.f;
            HDOT(rw, rs0, rs1, rs2, rs3)
            const int dy = 15 - d;                       // compile-time (unrolled)
            float cw0, cw1, cw2, cw3;
            CWEXT(dy, cw0, cw1, cw2, cw3)
            acc0 += cw0 * rs0;  acc1 += cw1 * rs1;
            acc2 += cw2 * rs2;  acc3 += cw3 * rs3;
        }

        *(float4*)&out[((size_t)(b * CC + c) * HH + yo) * WW + xo] =
            make_float4(acc0, acc1, acc2, acc3);
    }

#undef HDOT
#undef CWEXT
}

extern "C" void kernel_launch(void* const* d_in, const int* in_sizes, int n_in,
                              void* d_out, int out_size, void* d_ws, size_t ws_size,
                              hipStream_t stream) {
    const float* sharp = (const float*)d_in[0];
    const float* cocm  = (const float*)d_in[1];
    float* out = (float*)d_out;

    dim3 grid(WW / TXO, HH / TYO, BB);   // 8 x 32 x 4 = 1024 blocks
    dim3 block(16, 16, 1);
    defocus_kernel<<<grid, block, 0, stream>>>(sharp, cocm, out);
}

// Round 9
// 122.083 us; speedup vs baseline: 1.4498x; 1.0751x over previous
//
#include <hip/hip_runtime.h>
#include <math.h>

typedef _Float16 h2_t __attribute__((ext_vector_type(2)));
typedef _Float16 h4_t __attribute__((ext_vector_type(4)));
typedef _Float16 h8_t __attribute__((ext_vector_type(8)));

#define NP 32
#define KC 31
#define HH 512
#define WW 512
#define BB 4
#define CC 3

#define TXO 64        // 64-wide tile
#define TYO 16        // 16 output rows -> 256-thread block
#define NT 256        // threads per block
#define TROWS 46      // 16 outputs + 15 + 15 halo
#define TWORDS 48     // row stride in h2 words (4ty x 16tx quarter-wave covers
                      // all 32 banks exactly once -> conflict-free b64)
#define TILEW (TROWS * TWORDS)   // 2208 h2 words per channel tile
#define WSTR 36       // weight table plane stride in h2 words

// HARD CONSTRAINTS (measured R0-R8):
//  - grid z = BB; wj[64] -> VGPR cap must be >=128 (R7: (256,4) capped 64 ->
//    158MB spill). NOTHING long-lived across the compute loop (R1/R2/R3).
//  - Barriers not the bottleneck (R5). VALU count not the bottleneck (R6).
//  - R8 DIAGNOSIS: per-wave serialization. Each dy-iter = issue 18 ds_reads,
//    drain lgkmcnt, then ~292cyc VALU -> ~56% duty; VALUBusy 48% => ~1
//    effective wave/SIMD. R4's extra 28 VGPRs were the compiler's own read
//    pipeline; the R6 fold killed it (VGPR 128->100, dur unchanged).
// THIS ROUND: explicit 2-deep software pipeline in the dy-loop:
//   FOLD(cur in-place) -> ISSUE(next pair -> other buffer) -> sched_barrier
//   -> HDOT(cur). Next reads fly under the ~300cyc HDOT; next FOLD waits ~0.
// Arithmetic order identical -> bit-identical output. Peak regs ~130 (<256
// cap, no spill): folded cur 18 + next-in-flight 36 + wj 64 + accs/addr.

__device__ __forceinline__ double plane_of(int i) {
    const double stepd = 50.0 / 31.0;
    return (i < 31) ? (double)i * stepd : 50.0;
}

__device__ __forceinline__ h2_t mkh2(_Float16 a, _Float16 b) {
    h2_t r; r.x = a; r.y = b; return r;
}

__launch_bounds__(256, 2)
__global__ void defocus_kernel(const float* __restrict__ img,
                               const float* __restrict__ coc,
                               float* __restrict__ out) {
    const int tx = threadIdx.x;            // 0..15
    const int ty = threadIdx.y;            // 0..15
    const int tid = ty * 16 + tx;
    const int tilex = blockIdx.x * TXO;
    const int tiley = blockIdx.y * TYO;
    const int b = blockIdx.z;

    __shared__ __align__(16) h2_t wtab[NP * WSTR];   //  4608 B
    __shared__ __align__(16) h2_t tile[3 * TILEW];   // 26496 B (total 31104)

    const int yo = tiley + ty;
    const int xo = tilex + tx * 4;

    // ---- (1) coc load first; its latency hides under the wtab build
    const float4 cv = *(const float4*)&coc[((size_t)b * HH + yo) * WW + xo];

    // ---- (2) in-block wtab build (bit-identical values; 4 passes x 8 planes).
    {
        const int t = tid & 31;               // padded tap position 0..31
        #pragma unroll
        for (int pass = 0; pass < 4; ++pass) {
            const int p = (tid >> 5) + 8 * pass;    // plane 0..31
            const double stepd = 50.0 / 31.0;
            double cocp = (p < 31) ? (double)p * stepd : 50.0;  // numpy linspace
            float gt;
            if (cocp < 0.5) {
                gt = (t == 15) ? 1.f : 0.f;   // identity plane (plane 0 only)
            } else {
                double sigma = cocp / 2.355;
                int k = (int)(2.0 * cocp + 1.0);   // trunc, matches python int()
                if ((k & 1) == 0) k += 1;
                if (k > KC) k = KC;
                int h = k / 2;
                int d = t - 15;
                float denom = (float)(2.0 * sigma * sigma);
                float v = (d >= -h && d <= h && t < KC) ? expf(-(float)(d * d) / denom) : 0.f;
                float s = v;
                #pragma unroll
                for (int off = 1; off < 32; off <<= 1) s += __shfl_xor(s, off, 32);
                gt = v / s;
            }
            const int m = t & 15;
            const int s0 = (t < 16) ? (2 * m) : ((2 * m - 1 < 0) ? 0 : 2 * m - 1);
            const int s1 = (t < 16) ? (2 * m + 1) : (2 * m);
            float w0 = __shfl(gt, s0, 32);
            float w1 = __shfl(gt, s1, 32);
            if (t >= 16 && (2 * m - 1) < 0) w0 = 0.f;   // g[-1] = 0
            h2_t w; w.x = (_Float16)w0; w.y = (_Float16)w1;
            wtab[p * WSTR + t] = w;
            if (t < WSTR - 32) {
                h2_t z; z.x = (_Float16)0.f; z.y = (_Float16)0.f;
                wtab[p * WSTR + 32 + t] = z;
            }
        }
    }

    // ---- (3) per-pixel bin index, exact double-precision boundary semantics
    const float cocf[4] = {cv.x, cv.y, cv.z, cv.w};
    int idx[4];
    #pragma unroll
    for (int j = 0; j < 4; ++j) {
        const double stepd = 50.0 / 31.0;
        double cd = (double)cocf[j];
        int i0 = (int)floor(cd / stepd + 0.5);
        i0 = min(max(i0, 0), 31);
        if (i0 > 0 && cd <= 0.5 * (plane_of(i0 - 1) + plane_of(i0))) {
            i0 -= 1;
        } else if (i0 < 31 && cd > 0.5 * (plane_of(i0) + plane_of(i0 + 1))) {
            i0 += 1;
        }
        idx[j] = i0;
    }

    // Fence: forbid hoisting staging loads up across the f64 region (R1 spill).
    __builtin_amdgcn_sched_barrier(0);

    // ---- (4) stage ALL THREE channels into private tiles, back-to-back.
    #pragma unroll 1
    for (int c = 0; c < CC; ++c) {
        const float* src = img + (size_t)(b * CC + c) * HH * WW;
        h2_t* tdst = tile + c * TILEW;
        for (int f = tid; f < TILEW; f += NT) {
            int r = f / TWORDS;
            int w = f - r * TWORDS;
            int gy = tiley - 15 + r;
            int gx = tilex - 15 + 2 * w;
            float v0 = 0.f, v1 = 0.f;
            if ((unsigned)gy < (unsigned)HH) {
                if ((unsigned)gx < (unsigned)WW) v0 = src[gy * WW + gx];
                if ((unsigned)(gx + 1) < (unsigned)WW) v1 = src[gy * WW + gx + 1];
            }
            h2_t pv; pv.x = (_Float16)v0; pv.y = (_Float16)v1;
            tdst[f] = pv;
        }
    }

    __syncthreads();   // the ONLY barrier: wtab + all three tiles staged

    // ---- (5) gather this thread's 4 weight rows into registers
    // even local col (j=0,2): phase A; odd (j=1,3): phase B (pre-shifted one tap)
    h2_t wj[4][16];
    #pragma unroll
    for (int j = 0; j < 4; ++j) {
        const h2_t* wp = &wtab[idx[j] * WSTR + (j & 1) * 16];
        #pragma unroll
        for (int m = 0; m < 4; ++m) {
            h8_t v = *(const h8_t*)(wp + 4 * m);   // 16B aligned: WSTR%4==0
            #pragma unroll
            for (int q = 0; q < 4; ++q) {
                h2_t t2; t2.x = v[2 * q]; t2.y = v[2 * q + 1];
                wj[j][4 * m + q] = t2;
            }
        }
    }

// word I (h2) view of a folded h4 buffer F[9] -- pure register aliasing
#define RWW(F, I) mkh2(F[(I) >> 1][((I) & 1) * 2], F[(I) >> 1][((I) & 1) * 2 + 1])

// issue one row's 9 ds_read_b64 into an h4 buffer
#define ISSUE_ROW(DST, ROW)                                                  \
    {                                                                        \
        _Pragma("unroll")                                                    \
        for (int m = 0; m < 9; ++m)                                          \
            DST[m] = *(const h4_t*)(rowbase + (ROW) * TWORDS + 2 * m);       \
    }

#define ISSUE_PAIR(QA, QB, D)                                                \
    ISSUE_ROW(QA, 15 - (D))                                                  \
    ISSUE_ROW(QB, 15 + (D))

// in-place fold: QA[m] += QB[m]  (2x v_pk_add_f16 each; QA becomes the row)
#define FOLD(QA, QB)                                                         \
    {                                                                        \
        _Pragma("unroll")                                                    \
        for (int m = 0; m < 9; ++m) QA[m] = QA[m] + QB[m];                   \
    }

// horizontal dot on folded buffer F (words 0..16 used; rs2/3 shifted by 1)
#define HDOTF(F, RS0, RS1, RS2, RS3)                                         \
    {                                                                        \
        _Pragma("unroll")                                                    \
        for (int m = 0; m < 16; ++m) {                                       \
            RS0 = __builtin_amdgcn_fdot2(wj[0][m], RWW(F, m),     RS0, false);\
            RS1 = __builtin_amdgcn_fdot2(wj[1][m], RWW(F, m),     RS1, false);\
            RS2 = __builtin_amdgcn_fdot2(wj[2][m], RWW(F, m + 1), RS2, false);\
            RS3 = __builtin_amdgcn_fdot2(wj[3][m], RWW(F, m + 1), RS3, false);\
        }                                                                    \
    }

// column-weight extraction for compile-time DY (verified phase mapping)
#define CWEXT(DY, CW0, CW1, CW2, CW3)                                        \
    {                                                                        \
        if (((DY) & 1) == 0) {                                               \
            CW0 = (float)wj[0][(DY) >> 1].x;                                 \
            CW2 = (float)wj[2][(DY) >> 1].x;                                 \
            CW1 = (float)wj[1][(DY) >> 1].y;                                 \
            CW3 = (float)wj[3][(DY) >> 1].y;                                 \
        } else {                                                             \
            CW0 = (float)wj[0][(DY) >> 1].y;                                 \
            CW2 = (float)wj[2][(DY) >> 1].y;                                 \
            CW1 = (float)wj[1][((DY) + 1) >> 1].x;                           \
            CW3 = (float)wj[3][((DY) + 1) >> 1].x;                           \
        }                                                                    \
    }

// pipeline step for pair D: fold cur, issue pair D+1, fence, hdot, accumulate
#define STEP(D, CQA, CQB, NQA, NQB, DOISSUE)                                 \
    {                                                                        \
        FOLD(CQA, CQB)                                                       \
        if (DOISSUE) { ISSUE_PAIR(NQA, NQB, (D) + 1) }                       \
        __builtin_amdgcn_sched_barrier(0);                                   \
        float rs0 = 0.f, rs1 = 0.f, rs2 = 0.f, rs3 = 0.f;                    \
        HDOTF(CQA, rs0, rs1, rs2, rs3)                                       \
        float cw0, cw1, cw2, cw3;                                            \
        CWEXT(15 - (D), cw0, cw1, cw2, cw3)                                  \
        acc0 += cw0 * rs0;  acc1 += cw1 * rs1;                               \
        acc2 += cw2 * rs2;  acc3 += cw3 * rs3;                               \
    }

    // ---- (6) three compute passes; 2-deep pipelined symmetric fold
    #pragma unroll 1
    for (int c = 0; c < CC; ++c) {
        float acc0 = 0.f, acc1 = 0.f, acc2 = 0.f, acc3 = 0.f;
        const h2_t* rowbase = &tile[c * TILEW + ty * TWORDS + 2 * tx];

        h4_t Aqa[9], Aqb[9], Bqa[9], Bqb[9];

        // prologue: center row reads + pair-1 reads all in flight
        ISSUE_ROW(Aqa, 15)
        ISSUE_PAIR(Bqa, Bqb, 1)
        __builtin_amdgcn_sched_barrier(0);

        // center row (dy = 15): no fold, waits only on Aqa's 9 reads
        {
            float rs0 = 0.f, rs1 = 0.f, rs2 = 0.f, rs3 = 0.f;
            HDOTF(Aqa, rs0, rs1, rs2, rs3)
            float cw0, cw1, cw2, cw3;
            CWEXT(15, cw0, cw1, cw2, cw3)
            acc0 += cw0 * rs0;  acc1 += cw1 * rs1;
            acc2 += cw2 * rs2;  acc3 += cw3 * rs3;
        }

        STEP(1,  Bqa, Bqb, Aqa, Aqb, 1)
        STEP(2,  Aqa, Aqb, Bqa, Bqb, 1)
        STEP(3,  Bqa, Bqb, Aqa, Aqb, 1)
        STEP(4,  Aqa, Aqb, Bqa, Bqb, 1)
        STEP(5,  Bqa, Bqb, Aqa, Aqb, 1)
        STEP(6,  Aqa, Aqb, Bqa, Bqb, 1)
        STEP(7,  Bqa, Bqb, Aqa, Aqb, 1)
        STEP(8,  Aqa, Aqb, Bqa, Bqb, 1)
        STEP(9,  Bqa, Bqb, Aqa, Aqb, 1)
        STEP(10, Aqa, Aqb, Bqa, Bqb, 1)
        STEP(11, Bqa, Bqb, Aqa, Aqb, 1)
        STEP(12, Aqa, Aqb, Bqa, Bqb, 1)
        STEP(13, Bqa, Bqb, Aqa, Aqb, 1)
        STEP(14, Aqa, Aqb, Bqa, Bqb, 1)
        STEP(15, Bqa, Bqb, Aqa, Aqb, 0)

        *(float4*)&out[((size_t)(b * CC + c) * HH + yo) * WW + xo] =
            make_float4(acc0, acc1, acc2, acc3);
    }

#undef RWW
#undef ISSUE_ROW
#undef ISSUE_PAIR
#undef FOLD
#undef HDOTF
#undef CWEXT
#undef STEP
}

extern "C" void kernel_launch(void* const* d_in, const int* in_sizes, int n_in,
                              void* d_out, int out_size, void* d_ws, size_t ws_size,
                              hipStream_t stream) {
    const float* sharp = (const float*)d_in[0];
    const float* cocm  = (const float*)d_in[1];
    float* out = (float*)d_out;

    dim3 grid(WW / TXO, HH / TYO, BB);   // 8 x 32 x 4 = 1024 blocks
    dim3 block(16, 16, 1);
    defocus_kernel<<<grid, block, 0, stream>>>(sharp, cocm, out);
}